// Round 5
// baseline (235.168 us; speedup 1.0000x reference)
//
#include <hip/hip_runtime.h>

#define NC 32
#define DC 16
#define LSEQ 2048

// ---------------------------------------------------------------------------
// caps tail (runs in ONE block per b, 256 threads):
//   s[n][d] = sum_i v[n][i] * W[i][n*16+d];  o = s / sqrt(sum_d s^2 + 1e-7)
// UNIFORM: v is one 64-vec shared by all n (vS[64]); else vS[32][68] (padded).
// FINAL: write o to out; else wtil[b][n][i] = sum_d W[i][n*16+d]*o[n][d] -> wt.
// ---------------------------------------------------------------------------
template <int UNIFORM, int FINAL>
__device__ __forceinline__ void caps_tail(int b, int t,
                                          const float* __restrict__ W,
                                          const float* vS, float* oS,
                                          float* __restrict__ wt,
                                          float* __restrict__ outg) {
#pragma unroll
    for (int rep = 0; rep < 2; ++rep) {
        const int nd = t + 256 * rep;          // n = nd>>4, d = nd&15
        const float* vrow = UNIFORM ? vS : vS + (nd >> 4) * 68;
        float s = 0.f;
#pragma unroll 8
        for (int i = 0; i < 64; ++i)
            s = fmaf(vrow[i], W[i * (NC * DC) + nd], s);
        float s2 = s * s;
        s2 += __shfl_xor(s2, 1);
        s2 += __shfl_xor(s2, 2);
        s2 += __shfl_xor(s2, 4);
        s2 += __shfl_xor(s2, 8);
        const float o = s / sqrtf(s2 + 1e-7f);
        if (FINAL) outg[b * (NC * DC) + nd] = o;
        else       oS[nd] = o;
    }
    if (FINAL) return;
    __syncthreads();
#pragma unroll
    for (int rep = 0; rep < 8; ++rep) {
        const int idx = t + 256 * rep;         // n = idx>>6, i = idx&63
        const int n = idx >> 6, i = idx & 63;
        const float4* wr = (const float4*)(W + i * (NC * DC) + n * DC);
        const float4* o4 = (const float4*)(oS + n * DC);
        float acc = 0.f;
#pragma unroll
        for (int q = 0; q < 4; ++q) {
            float4 wv = wr[q], ov = o4[q];
            acc += wv.x * ov.x + wv.y * ov.y + wv.z * ov.z + wv.w * ov.w;
        }
        wt[b * (NC * 64) + idx] = acc;
    }
}

// ---------------------------------------------------------------------------
// K1: column partial sums of u per 64-l chunk -> v0p[gb][64] (plain stores);
// last arriver of the 32 chunks folds and runs caps0 (uniform c = 1/32) -> wt.
// grid 1024: b = (rid&7)+8*(rid>>8) (XCD-grouped), j = (rid>>3)&31.
// ---------------------------------------------------------------------------
__global__ __launch_bounds__(256) void k_sum(const float* __restrict__ u,
                                             const float* __restrict__ W,
                                             float* __restrict__ v0p,
                                             float* __restrict__ wt,
                                             int* __restrict__ ctr) {
    const int rid = blockIdx.x;
    const int b = (rid & 7) + ((rid >> 8) << 3);
    const int j = (rid >> 3) & 31;
    const int t = threadIdx.x;
    __shared__ float red[16][64];
    __shared__ float vS[64];
    __shared__ float oS[512];
    __shared__ int amLast;

    const float4* ug = (const float4*)(u + (b * LSEQ + j * 64) * 64);
    float4 a = {0.f, 0.f, 0.f, 0.f};
#pragma unroll
    for (int r = 0; r < 4; ++r) {
        float4 x = ug[t + 256 * r];            // col4 = t&15 fixed per thread
        a.x += x.x; a.y += x.y; a.z += x.z; a.w += x.w;
    }
    const int col4 = t & 15, r16 = t >> 4;
    red[r16][col4 * 4 + 0] = a.x;
    red[r16][col4 * 4 + 1] = a.y;
    red[r16][col4 * 4 + 2] = a.z;
    red[r16][col4 * 4 + 3] = a.w;
    __syncthreads();
    if (t < 64) {
        float s = 0.f;
#pragma unroll
        for (int rr = 0; rr < 16; ++rr) s += red[rr][t];
        v0p[(b * 32 + j) * 64 + t] = s;
    }
    __syncthreads();                           // drain stores (vmcnt 0 at barrier)
    if (t == 0) {
        __threadfence();                       // release
        amLast = (atomicAdd(&ctr[b * 32 + 0], 1) == 31);
    }
    __syncthreads();
    if (!amLast) return;
    __threadfence();                           // acquire

    if (t < 64) {
        float s = 0.f;
#pragma unroll 8
        for (int ch = 0; ch < 32; ++ch) s += v0p[(b * 32 + ch) * 64 + t];
        vS[t] = s * (1.f / 32.f);
    }
    __syncthreads();
    caps_tail<1, 0>(b, t, W, vS, oS, wt, nullptr);
}

// ---------------------------------------------------------------------------
// Route: grid 1024 (64 l's per block), 256 threads = 4 waves -> with 37.4 KB
// LDS: 4 blocks/CU = 16 waves/CU = 4 waves/SIMD. Head: load wt[b] (8 KB) +
// u chunk. Phase A: per-lane 2l x 4n logits (n = lc+8*jj -> conflict-free wf
// AND av reads). Softmax in-register. Phase B: per-lane 4n x 8d Vu tile.
// Tail: 4->2->1 cross-wave LDS fold, plain store to vpart[gb][2048]; last
// arriver of 32 folds vpart -> caps -> wt (or out if FINAL).
// ---------------------------------------------------------------------------
template <int PH, int FINAL>
__global__ __launch_bounds__(256, 4) void k_route(const float* __restrict__ u,
                                                  const float* __restrict__ W,
                                                  const float* __restrict__ wt_in,
                                                  float* __restrict__ vpart,
                                                  float* __restrict__ wt_out,
                                                  float* __restrict__ outg,
                                                  int* __restrict__ ctr) {
    const int rid = blockIdx.x;
    const int b = (rid & 7) + ((rid >> 8) << 3);
    const int j = (rid >> 3) & 31;
    const int gb = b * 32 + j;
    const int t = threadIdx.x;
    const int w = t >> 6, lane = t & 63;

    __shared__ float uS[64 * 68];      // 17408 B; reused as red[2][32*68] / vS
    __shared__ float wS[32 * 68];      // 8704 B
    __shared__ float cS[64 * 36];      // 9216 B (c rows stride 9 float4)
    __shared__ float oS[512];
    __shared__ int amLast;
    float4* uS4 = (float4*)uS;
    float4* wS4 = (float4*)wS;
    float4* c4  = (float4*)cS;

    // ---- stage u chunk [64][64] and wtil tile [32][64] (coalesced) ----
    const float4* ug = (const float4*)(u + (b * LSEQ + j * 64) * 64);
#pragma unroll
    for (int r = 0; r < 4; ++r) {
        int idx = t + 256 * r;
        uS4[(idx >> 4) * 17 + (idx & 15)] = ug[idx];
    }
    const float4* wg = (const float4*)(wt_in + b * (NC * 64));
#pragma unroll
    for (int r = 0; r < 2; ++r) {
        int idx = t + 256 * r;
        wS4[(idx >> 4) * 17 + (idx & 15)] = wg[idx];
    }
    __syncthreads();

    // ---- phase A: per-lane 2l x 4n logits; l = w*16+lr+8i, n = lc+8*jj ----
    const int lr = lane & 7, lc = lane >> 3;
    const int lw = w * 16;
    float acc[2][4];
#pragma unroll
    for (int i = 0; i < 2; ++i)
#pragma unroll
        for (int jj = 0; jj < 4; ++jj) acc[i][jj] = 0.f;
#pragma unroll 4
    for (int k4 = 0; k4 < 16; ++k4) {
        float4 wf[4];
#pragma unroll
        for (int jj = 0; jj < 4; ++jj) wf[jj] = wS4[(lc + 8 * jj) * 17 + k4];
#pragma unroll
        for (int i = 0; i < 2; ++i) {
            float4 av = uS4[(lw + lr + 8 * i) * 17 + k4];
#pragma unroll
            for (int jj = 0; jj < 4; ++jj) {
                acc[i][jj] = fmaf(av.x, wf[jj].x, acc[i][jj]);
                acc[i][jj] = fmaf(av.y, wf[jj].y, acc[i][jj]);
                acc[i][jj] = fmaf(av.z, wf[jj].z, acc[i][jj]);
                acc[i][jj] = fmaf(av.w, wf[jj].w, acc[i][jj]);
            }
        }
    }

    // ---- softmax over n per l-row (reg-reduce + shfl over lc bits) ----
#pragma unroll
    for (int i = 0; i < 2; ++i) {
        float m = fmaxf(fmaxf(acc[i][0], acc[i][1]), fmaxf(acc[i][2], acc[i][3]));
        m = fmaxf(m, __shfl_xor(m, 8));
        m = fmaxf(m, __shfl_xor(m, 16));
        m = fmaxf(m, __shfl_xor(m, 32));
        float e0 = __expf(acc[i][0] - m), e1 = __expf(acc[i][1] - m);
        float e2 = __expf(acc[i][2] - m), e3 = __expf(acc[i][3] - m);
        float ss = e0 + e1 + e2 + e3;
        ss += __shfl_xor(ss, 8);
        ss += __shfl_xor(ss, 16);
        ss += __shfl_xor(ss, 32);
        float inv = 1.f / ss;
        float4 cv = {e0 * inv, e1 * inv, e2 * inv, e3 * inv};
        c4[(lw + lr + 8 * i) * 9 + lc] = cv;   // xyzw = n = lc, lc+8, lc+16, lc+24
    }
    __syncthreads();

    // ---- phase B: Vu[n][i8] = sum_l c[l][n]*u[l][i8]; n = ng+8*jj ----
    const int dr = lane & 7, ng = lane >> 3;
    float vacc[4][8];
#pragma unroll
    for (int jj = 0; jj < 4; ++jj)
#pragma unroll
        for (int k = 0; k < 8; ++k) vacc[jj][k] = 0.f;
#pragma unroll
    for (int lrel = 0; lrel < 16; ++lrel) {
        const int row = lw + lrel;
        float4 cv = c4[row * 9 + ng];
        const float4* up = uS4 + row * 17 + dr * 2;
        float4 u0 = up[0], u1 = up[1];
        const float* cp = (const float*)&cv;
#pragma unroll
        for (int jj = 0; jj < 4; ++jj) {
            float c = cp[jj];
            vacc[jj][0] = fmaf(c, u0.x, vacc[jj][0]);
            vacc[jj][1] = fmaf(c, u0.y, vacc[jj][1]);
            vacc[jj][2] = fmaf(c, u0.z, vacc[jj][2]);
            vacc[jj][3] = fmaf(c, u0.w, vacc[jj][3]);
            vacc[jj][4] = fmaf(c, u1.x, vacc[jj][4]);
            vacc[jj][5] = fmaf(c, u1.y, vacc[jj][5]);
            vacc[jj][6] = fmaf(c, u1.z, vacc[jj][6]);
            vacc[jj][7] = fmaf(c, u1.w, vacc[jj][7]);
        }
    }
    __syncthreads();                   // all uS reads done -> overlay red on uS

    // ---- cross-wave fold: waves 1,3 write; 0,2 add; halves fold + store ----
    float* red = uS;                   // [2][32 rows * 68]
    float* rbase = red + (w >> 1) * 2176;
    if (w & 1) {
#pragma unroll
        for (int jj = 0; jj < 4; ++jj) {
            float4* rp = (float4*)(rbase + (ng + 8 * jj) * 68 + dr * 8);
            float4 r0 = {vacc[jj][0], vacc[jj][1], vacc[jj][2], vacc[jj][3]};
            float4 r1 = {vacc[jj][4], vacc[jj][5], vacc[jj][6], vacc[jj][7]};
            rp[0] = r0;
            rp[1] = r1;
        }
    }
    __syncthreads();
    if (!(w & 1)) {
#pragma unroll
        for (int jj = 0; jj < 4; ++jj) {
            float4* rp = (float4*)(rbase + (ng + 8 * jj) * 68 + dr * 8);
            float4 r0 = rp[0], r1 = rp[1];
            r0.x += vacc[jj][0]; r0.y += vacc[jj][1];
            r0.z += vacc[jj][2]; r0.w += vacc[jj][3];
            r1.x += vacc[jj][4]; r1.y += vacc[jj][5];
            r1.z += vacc[jj][6]; r1.w += vacc[jj][7];
            rp[0] = r0;
            rp[1] = r1;
        }
    }
    __syncthreads();
    {
        float4* vp4 = (float4*)(vpart + gb * 2048);
#pragma unroll
        for (int r = 0; r < 2; ++r) {
            int idx = t + 256 * r;             // 0..511: n = idx>>4, c4i = idx&15
            int s17 = (idx >> 4) * 17 + (idx & 15);
            float4 x = ((float4*)uS)[s17];
            float4 y = ((float4*)(uS + 2176))[s17];
            float4 o = {x.x + y.x, x.y + y.y, x.z + y.z, x.w + y.w};
            vp4[idx] = o;
        }
    }
    __syncthreads();                   // drain global stores before signaling

    if (t == 0) {
        __threadfence();               // release
        amLast = (atomicAdd(&ctr[b * 32 + PH], 1) == 31);
    }
    __syncthreads();
    if (!amLast) return;
    __threadfence();                   // acquire

    // ---- folder: fold 32 chunk partials -> vS[32][68] (= uS), then caps ----
    float* vS = uS;
    const float4* vpb = (const float4*)(vpart + b * 32 * 2048);
#pragma unroll
    for (int r = 0; r < 2; ++r) {
        int idx = t + 256 * r;
        float4 s = {0.f, 0.f, 0.f, 0.f};
#pragma unroll 8
        for (int ch = 0; ch < 32; ++ch) {
            float4 x = vpb[ch * 512 + idx];
            s.x += x.x; s.y += x.y; s.z += x.z; s.w += x.w;
        }
        ((float4*)vS)[(idx >> 4) * 17 + (idx & 15)] = s;
    }
    __syncthreads();
    caps_tail<0, FINAL>(b, t, W, vS, oS, wt_out, outg);
}

extern "C" void kernel_launch(void* const* d_in, const int* in_sizes, int n_in,
                              void* d_out, int out_size, void* d_ws, size_t ws_size,
                              hipStream_t stream) {
    const float* u = (const float*)d_in[0];  // [32, 2048, 64] f32
    const float* W = (const float*)d_in[1];  // [1, 64, 512]  f32
    float* out = (float*)d_out;              // [32, 32, 16]  f32
    float* ws  = (float*)d_ws;
    int*   ctr   = (int*)ws;                   // 1024 ints (slots 0..2 per b)
    float* v0p   = ws + 1024;                  // 1024*64   = 65536 floats
    float* wt    = ws + 1024 + 65536;          // 32*2048   = 65536 floats
    float* vpart = ws + 1024 + 65536 + 65536;  // 1024*2048 = 2097152 floats

    hipMemsetAsync(ctr, 0, 1024 * sizeof(int), stream);

    k_sum<<<1024, 256, 0, stream>>>(u, W, v0p, wt, ctr);
    k_route<1, 0><<<1024, 256, 0, stream>>>(u, W, wt, vpart, wt, nullptr, ctr);
    k_route<2, 1><<<1024, 256, 0, stream>>>(u, W, wt, vpart, nullptr, out, ctr);
}

// Round 6
// 99.595 us; speedup vs baseline: 2.3612x; 2.3612x over previous
//
#include <hip/hip_runtime.h>

#define NC 32
#define DC 16
#define LSEQ 2048

// ---------------------------------------------------------------------------
// k_sum_u: per-block partial column sums of u over 256 l's.
// grid 256 (b = bid>>3, chunk = bid&7), 256 threads. Writes v0p[bid][64].
// ---------------------------------------------------------------------------
__global__ __launch_bounds__(256) void k_sum_u(const float* __restrict__ u,
                                               float* __restrict__ v0p) {
    int b  = blockIdx.x >> 3;
    int l0 = (blockIdx.x & 7) * 256;
    int q  = threadIdx.x & 15;   // float4 column
    int r  = threadIdx.x >> 4;   // row offset 0..15
    const float4* u4 = (const float4*)u;
    float4 acc = {0.f, 0.f, 0.f, 0.f};
#pragma unroll
    for (int j = 0; j < 16; ++j) {
        int l = l0 + r + 16 * j;
        float4 x = u4[(b * LSEQ + l) * 16 + q];
        acc.x += x.x; acc.y += x.y; acc.z += x.z; acc.w += x.w;
    }
    __shared__ float red[16][64];
    red[r][q * 4 + 0] = acc.x;
    red[r][q * 4 + 1] = acc.y;
    red[r][q * 4 + 2] = acc.z;
    red[r][q * 4 + 3] = acc.w;
    __syncthreads();
    if (threadIdx.x < 64) {
        float s = 0.f;
#pragma unroll
        for (int rr = 0; rr < 16; ++rr) s += red[rr][threadIdx.x];
        v0p[blockIdx.x * 64 + threadIdx.x] = s;   // partial, no atomics
    }
}

// ---------------------------------------------------------------------------
// k_caps: fold partials -> v[b][n][64]; s = v@W_n; o = L2-normalize(s);
// wtil[b][n][i] = (W_n @ o_n)[i]  (unless FINAL: write o to out).
// grid 256 (b = bid>>3, ng = bid&7 -> capsules ng*4..ng*4+3), 64 threads.
// ---------------------------------------------------------------------------
template <bool BCAST, bool FINAL>
__global__ __launch_bounds__(64) void k_caps(const float* __restrict__ v,
                                             const float* __restrict__ W,
                                             float* __restrict__ wtil,
                                             float* __restrict__ out,
                                             float vscale) {
    int b  = blockIdx.x >> 3;
    int ng = blockIdx.x & 7;
    int t  = threadIdx.x;
    __shared__ float vS[4][72];   // 72-float row stride: float4-aligned, pad
    __shared__ float oS[4][16];
    if (BCAST) {
        // fold 8 partial sums of k_sum_u
        float s = 0.f;
#pragma unroll
        for (int ch = 0; ch < 8; ++ch) s += v[(b * 8 + ch) * 64 + t];
        s *= vscale;
#pragma unroll
        for (int n4 = 0; n4 < 4; ++n4) vS[n4][t] = s;   // replicate
    } else {
        // fold 16 route partials: v layout [b][ch][n*64+d], need rows ng*4..+3
        int row = t >> 4, col4 = t & 15;
        const float4* v4 = (const float4*)v;
        float4 a = {0.f, 0.f, 0.f, 0.f};
#pragma unroll
        for (int ch = 0; ch < 16; ++ch) {
            float4 x = v4[(b * 16 + ch) * 512 + (ng * 4 + row) * 16 + col4];
            a.x += x.x; a.y += x.y; a.z += x.z; a.w += x.w;
        }
        ((float4*)&vS[row][0])[col4] = a;
    }
    __syncthreads();
    int n4 = t >> 4, d = t & 15;
    int n  = ng * 4 + n4;
    const float* vrow = &vS[n4][0];
    float s = 0.f;
#pragma unroll
    for (int i = 0; i < 64; ++i)
        s = fmaf(vrow[i], W[i * (NC * DC) + n * DC + d], s);
    float s2 = s * s;
#pragma unroll
    for (int off = 8; off >= 1; off >>= 1) s2 += __shfl_xor(s2, off, 16);
    float o = s / sqrtf(s2 + 1e-7f);
    if (FINAL) {
        out[b * (NC * DC) + n * DC + d] = o;
    } else {
        oS[n4][d] = o;
        __syncthreads();
        // wtil[b][n][i]: thread (n4, i4 = t&15) computes i = i4*4..i4*4+3
        int i4 = t & 15;
        float4 wv;
        float* wvp = (float*)&wv;
#pragma unroll
        for (int k = 0; k < 4; ++k) {
            int i = i4 * 4 + k;
            float acc = 0.f;
#pragma unroll
            for (int dd = 0; dd < 16; ++dd)
                acc = fmaf(W[i * (NC * DC) + n * DC + dd], oS[n4][dd], acc);
            wvp[k] = acc;
        }
        ((float4*)wtil)[(b * (NC * 64) + n * 64 + i4 * 4) >> 2] = wv;
    }
}

// ---------------------------------------------------------------------------
// k_route v6: grid 512 (b = bid>>4, ch = bid&15 -> 128 l's), 256 threads =
// 4 waves (2 waves/SIMD at 2 blocks/CU); wave w owns l-rows [w*32, w*32+32).
// Phase A: per-lane 4l x 4n logits, n = lc + 8*jj (bank-conflict-free wf),
//          in-register softmax over n (shfl_xor over lc bits), c -> cS.
// Phase B: per-lane 4n x 8d V-tile over the wave's 32 l's.
// Fold: waves {1,3} write, {0,2} add (red overlays uS), halves fold + store
// block partial V[32][64] -> vpart[bid][2048]. No atomics, no fences.
// ---------------------------------------------------------------------------
__global__ __launch_bounds__(256) void k_route(const float* __restrict__ u,
                                               const float* __restrict__ wtil,
                                               float* __restrict__ vpart) {
    int b    = blockIdx.x >> 4;
    int ch   = blockIdx.x & 15;
    int l0   = ch * 128;
    int t    = threadIdx.x;
    int w    = t >> 6;
    int lane = t & 63;
    int lr   = lane & 7;   // l = w*32 + lr + 8*i
    int lc   = lane >> 3;  // n = lc + 8*jj
    int dr   = lane & 7;   // phase B: d = dr*8 .. dr*8+7
    int ng   = lane >> 3;  // phase B: n = ng + 8*jj

    __shared__ float uS[128 * 68];        // 34816 B; red[2][2048] overlay later
    __shared__ float wS[32 * 68];         //  8704 B
    __shared__ float cS[128 * 36];        // 18432 B: c rows, stride 9 float4
    float4* uS4 = (float4*)uS;
    float4* wS4 = (float4*)wS;
    float4* c4  = (float4*)cS;

    // ---- stage u-tile [128][64] and w-tile [32][64] (coalesced) ----
    const float4* ug = (const float4*)(u + (b * LSEQ + l0) * 64);
#pragma unroll
    for (int r = 0; r < 8; ++r) {
        int idx = t + 256 * r;                 // 0..2047 = row*16 + col4
        uS4[(idx >> 4) * 17 + (idx & 15)] = ug[idx];
    }
    const float4* wg = (const float4*)(wtil + b * (NC * 64));
#pragma unroll
    for (int r = 0; r < 2; ++r) {
        int idx = t + 256 * r;                 // 0..511
        wS4[(idx >> 4) * 17 + (idx & 15)] = wg[idx];
    }
    __syncthreads();

    // ---- phase A: logits (per-lane 4l x 4n register tile) ----
    float acc[4][4];
#pragma unroll
    for (int i = 0; i < 4; ++i)
#pragma unroll
        for (int jj = 0; jj < 4; ++jj) acc[i][jj] = 0.f;
    int arow = w * 32 + lr;
#pragma unroll 4
    for (int k4 = 0; k4 < 16; ++k4) {
        float4 wf[4];
#pragma unroll
        for (int jj = 0; jj < 4; ++jj) wf[jj] = wS4[(lc + 8 * jj) * 17 + k4];
#pragma unroll
        for (int i = 0; i < 4; ++i) {
            float4 a = uS4[(arow + 8 * i) * 17 + k4];
#pragma unroll
            for (int jj = 0; jj < 4; ++jj) {
                acc[i][jj] = fmaf(a.x, wf[jj].x, acc[i][jj]);
                acc[i][jj] = fmaf(a.y, wf[jj].y, acc[i][jj]);
                acc[i][jj] = fmaf(a.z, wf[jj].z, acc[i][jj]);
                acc[i][jj] = fmaf(a.w, wf[jj].w, acc[i][jj]);
            }
        }
    }

    // ---- softmax over n (4 regs x 8 lc-groups) per l-row i ----
#pragma unroll
    for (int i = 0; i < 4; ++i) {
        float m = fmaxf(fmaxf(acc[i][0], acc[i][1]), fmaxf(acc[i][2], acc[i][3]));
        m = fmaxf(m, __shfl_xor(m, 8));
        m = fmaxf(m, __shfl_xor(m, 16));
        m = fmaxf(m, __shfl_xor(m, 32));
        float e0 = __expf(acc[i][0] - m), e1 = __expf(acc[i][1] - m);
        float e2 = __expf(acc[i][2] - m), e3 = __expf(acc[i][3] - m);
        float ss = e0 + e1 + e2 + e3;
        ss += __shfl_xor(ss, 8);
        ss += __shfl_xor(ss, 16);
        ss += __shfl_xor(ss, 32);
        float inv = 1.f / ss;
        float4 cvv = {e0 * inv, e1 * inv, e2 * inv, e3 * inv};
        c4[(arow + 8 * i) * 9 + lc] = cvv;     // xyzw = n = lc, lc+8, lc+16, lc+24
    }
    __syncthreads();

    // ---- phase B: V[n = ng+8jj][d = dr*8..+7] += sum_l c[l][n]*u[l][d] ----
    float vacc[4][8];
#pragma unroll
    for (int jj = 0; jj < 4; ++jj)
#pragma unroll
        for (int k = 0; k < 8; ++k) vacc[jj][k] = 0.f;
#pragma unroll 8
    for (int lrel = 0; lrel < 32; ++lrel) {
        int row = w * 32 + lrel;
        float4 cv = c4[row * 9 + ng];
        const float4* ur = uS4 + row * 17 + dr * 2;
        float4 u0 = ur[0], u1 = ur[1];
        float* cp = (float*)&cv;
#pragma unroll
        for (int jj = 0; jj < 4; ++jj) {
            float c = cp[jj];
            vacc[jj][0] = fmaf(c, u0.x, vacc[jj][0]);
            vacc[jj][1] = fmaf(c, u0.y, vacc[jj][1]);
            vacc[jj][2] = fmaf(c, u0.z, vacc[jj][2]);
            vacc[jj][3] = fmaf(c, u0.w, vacc[jj][3]);
            vacc[jj][4] = fmaf(c, u1.x, vacc[jj][4]);
            vacc[jj][5] = fmaf(c, u1.y, vacc[jj][5]);
            vacc[jj][6] = fmaf(c, u1.z, vacc[jj][6]);
            vacc[jj][7] = fmaf(c, u1.w, vacc[jj][7]);
        }
    }
    __syncthreads();                   // all uS reads done -> overlay red on uS

    // ---- cross-wave fold: waves 1,3 write; 0,2 add; halves fold + store ----
    float* red   = uS;                 // [2][32][64] floats (16 KB)
    float* rbase = red + (w >> 1) * 2048;
    if (w & 1) {
#pragma unroll
        for (int jj = 0; jj < 4; ++jj) {
            float4* rp = (float4*)(rbase + (ng + 8 * jj) * 64 + dr * 8);
            float4 r0 = {vacc[jj][0], vacc[jj][1], vacc[jj][2], vacc[jj][3]};
            float4 r1 = {vacc[jj][4], vacc[jj][5], vacc[jj][6], vacc[jj][7]};
            rp[0] = r0;
            rp[1] = r1;
        }
    }
    __syncthreads();
    if (!(w & 1)) {
#pragma unroll
        for (int jj = 0; jj < 4; ++jj) {
            float4* rp = (float4*)(rbase + (ng + 8 * jj) * 64 + dr * 8);
            float4 r0 = rp[0], r1 = rp[1];
            r0.x += vacc[jj][0]; r0.y += vacc[jj][1];
            r0.z += vacc[jj][2]; r0.w += vacc[jj][3];
            r1.x += vacc[jj][4]; r1.y += vacc[jj][5];
            r1.z += vacc[jj][6]; r1.w += vacc[jj][7];
            rp[0] = r0;
            rp[1] = r1;
        }
    }
    __syncthreads();
    // fold the 2 halves and store the block partial (coalesced)
    float4* red4 = (float4*)red;
    float4* vp4  = (float4*)(vpart + blockIdx.x * 2048);
#pragma unroll
    for (int s = 0; s < 2; ++s) {
        int idx4 = t + 256 * s;               // 0..511
        float4 a  = red4[idx4];
        float4 c2 = red4[512 + idx4];
        float4 o  = {a.x + c2.x, a.y + c2.y, a.z + c2.z, a.w + c2.w};
        vp4[idx4] = o;
    }
}

extern "C" void kernel_launch(void* const* d_in, const int* in_sizes, int n_in,
                              void* d_out, int out_size, void* d_ws, size_t ws_size,
                              hipStream_t stream) {
    const float* u = (const float*)d_in[0];  // [32, 2048, 64] f32
    const float* W = (const float*)d_in[1];  // [1, 64, 512]  f32
    float* out = (float*)d_out;              // [32, 32, 16]  f32
    float* ws  = (float*)d_ws;
    float* v0p   = ws;                 // 256*64      = 16384 floats
    float* wt    = ws + 16384;         // 32*32*64    = 65536 floats
    float* vpart = ws + 16384 + 65536; // 512*2048    = 1048576 floats (~4 MB)

    // iter 0: uniform c = 1/32 -> column sum
    k_sum_u<<<256, 256, 0, stream>>>(u, v0p);
    k_caps<true, false><<<256, 64, 0, stream>>>(v0p, W, wt, nullptr, 1.0f / 32.0f);
    // iter 1
    k_route<<<512, 256, 0, stream>>>(u, wt, vpart);
    k_caps<false, false><<<256, 64, 0, stream>>>(vpart, W, wt, nullptr, 1.0f);
    // iter 2
    k_route<<<512, 256, 0, stream>>>(u, wt, vpart);
    k_caps<false, true><<<256, 64, 0, stream>>>(vpart, W, nullptr, out, 1.0f);
}